// Round 2
// baseline (1965.800 us; speedup 1.0000x reference)
//
#include <hip/hip_runtime.h>
#include <hip/hip_bf16.h>

// R2: fp32 inputs/outputs (per reference dtypes). Split-bf16 (hi+lo) MFMA for
// proj and scores (3-term Markidis => ~fp32 accuracy); P split hi/lo for PV.
// ws layout (96 MiB): [proj_hi bf16][proj_lo bf16][xT bf16], each B*L*D.

typedef __hip_bfloat16 bf16;
typedef float f32x4 __attribute__((ext_vector_type(4)));
typedef short bf16x8 __attribute__((ext_vector_type(8)));

#define MFMA16(A, B, C) __builtin_amdgcn_mfma_f32_16x16x32_bf16((A), (B), (C), 0, 0, 0)

static constexpr int B_ = 8;
static constexpr int L_ = 2048;
static constexpr int D_ = 1024;
#define NEGF (-1e30f)

__device__ __forceinline__ bf16 f2bf(float v) { return __float2bfloat16(v); }
__device__ __forceinline__ float bf2f(bf16 h) { return __bfloat162float(h); }

// ---------------- K0: transpose x[B][L][D] fp32 -> xT[B][D][L] bf16 ----------------
__global__ __launch_bounds__(256) void transpose_kernel(const float* __restrict__ x,
                                                        bf16* __restrict__ xT) {
  __shared__ bf16 t[32][40];
  const int b = blockIdx.z;
  const int j0 = blockIdx.x << 5, d0 = blockIdx.y << 5;
  const int tid = threadIdx.x;
  const int r = tid >> 3, c = (tid & 7) << 2;
  float4 v = *(const float4*)&x[((size_t)(b * L_ + j0 + r)) * D_ + d0 + c];
  t[r][c + 0] = f2bf(v.x); t[r][c + 1] = f2bf(v.y);
  t[r][c + 2] = f2bf(v.z); t[r][c + 3] = f2bf(v.w);
  __syncthreads();
  union { bf16 h[4]; uint2 u; } o;
  o.h[0] = t[c + 0][r]; o.h[1] = t[c + 1][r];
  o.h[2] = t[c + 2][r]; o.h[3] = t[c + 3][r];
  *(uint2*)&xT[((size_t)(b * D_ + d0 + r)) * L_ + j0 + c] = o.u;
}

// ---------------- K1: proj = relu(x @ W^T + b), split-bf16 3-term GEMM ----------------
// Writes proj_hi = bf16(proj), proj_lo = bf16(proj - proj_hi).
__global__ __launch_bounds__(256, 2) void proj_kernel(const float* __restrict__ x,
                                                      const float* __restrict__ W,
                                                      const float* __restrict__ bias,
                                                      bf16* __restrict__ ph_out,
                                                      bf16* __restrict__ pl_out) {
  const int m0 = blockIdx.x << 6, n0 = blockIdx.y << 6;
  __shared__ bf16 Ah[64 * 40], Al[64 * 40], Bh[64 * 40], Bl[64 * 40];
  const int tid = threadIdx.x;
  const int wave = tid >> 6, lane = tid & 63;
  const int wr = wave >> 1, wc = wave & 1;
  const int quad = lane >> 4, l16 = lane & 15;
  const int srow = tid >> 2, scol = (tid & 3) << 3;

  f32x4 acc[2][2];
#pragma unroll
  for (int mt = 0; mt < 2; ++mt)
#pragma unroll
    for (int nt = 0; nt < 2; ++nt) acc[mt][nt] = (f32x4){0.f, 0.f, 0.f, 0.f};

  const float* xrow = &x[(size_t)(m0 + srow) * D_];
  const float* wrow = &W[(size_t)(n0 + srow) * D_];

  for (int kc = 0; kc < D_; kc += 32) {
    {
      float4 va = *(const float4*)&xrow[kc + scol];
      float4 vb = *(const float4*)&xrow[kc + scol + 4];
      float vs[8] = {va.x, va.y, va.z, va.w, vb.x, vb.y, vb.z, vb.w};
      union { bf16 h[8]; uint4 u; } H, Lo;
#pragma unroll
      for (int i = 0; i < 8; ++i) { H.h[i] = f2bf(vs[i]); Lo.h[i] = f2bf(vs[i] - bf2f(H.h[i])); }
      *(uint4*)&Ah[srow * 40 + scol] = H.u;
      *(uint4*)&Al[srow * 40 + scol] = Lo.u;
      float4 wa = *(const float4*)&wrow[kc + scol];
      float4 wb = *(const float4*)&wrow[kc + scol + 4];
      float ws8[8] = {wa.x, wa.y, wa.z, wa.w, wb.x, wb.y, wb.z, wb.w};
#pragma unroll
      for (int i = 0; i < 8; ++i) { H.h[i] = f2bf(ws8[i]); Lo.h[i] = f2bf(ws8[i] - bf2f(H.h[i])); }
      *(uint4*)&Bh[srow * 40 + scol] = H.u;
      *(uint4*)&Bl[srow * 40 + scol] = Lo.u;
    }
    __syncthreads();
    bf16x8 ah0 = *(const bf16x8*)&Ah[(wr * 32 + l16) * 40 + quad * 8];
    bf16x8 ah1 = *(const bf16x8*)&Ah[(wr * 32 + 16 + l16) * 40 + quad * 8];
    bf16x8 al0 = *(const bf16x8*)&Al[(wr * 32 + l16) * 40 + quad * 8];
    bf16x8 al1 = *(const bf16x8*)&Al[(wr * 32 + 16 + l16) * 40 + quad * 8];
    bf16x8 bh0 = *(const bf16x8*)&Bh[(wc * 32 + l16) * 40 + quad * 8];
    bf16x8 bh1 = *(const bf16x8*)&Bh[(wc * 32 + 16 + l16) * 40 + quad * 8];
    bf16x8 bl0 = *(const bf16x8*)&Bl[(wc * 32 + l16) * 40 + quad * 8];
    bf16x8 bl1 = *(const bf16x8*)&Bl[(wc * 32 + 16 + l16) * 40 + quad * 8];
    // 3-term split: h*h + h*l + l*h per output tile
    acc[0][0] = MFMA16(ah0, bh0, acc[0][0]);
    acc[0][1] = MFMA16(ah0, bh1, acc[0][1]);
    acc[1][0] = MFMA16(ah1, bh0, acc[1][0]);
    acc[1][1] = MFMA16(ah1, bh1, acc[1][1]);
    acc[0][0] = MFMA16(ah0, bl0, acc[0][0]);
    acc[0][1] = MFMA16(ah0, bl1, acc[0][1]);
    acc[1][0] = MFMA16(ah1, bl0, acc[1][0]);
    acc[1][1] = MFMA16(ah1, bl1, acc[1][1]);
    acc[0][0] = MFMA16(al0, bh0, acc[0][0]);
    acc[0][1] = MFMA16(al0, bh1, acc[0][1]);
    acc[1][0] = MFMA16(al1, bh0, acc[1][0]);
    acc[1][1] = MFMA16(al1, bh1, acc[1][1]);
    __syncthreads();
  }
#pragma unroll
  for (int mt = 0; mt < 2; ++mt) {
#pragma unroll
    for (int nt = 0; nt < 2; ++nt) {
      const int n = n0 + wc * 32 + nt * 16 + l16;
      const float bv = bias[n];
#pragma unroll
      for (int r = 0; r < 4; ++r) {
        const int m = m0 + wr * 32 + mt * 16 + quad * 4 + r;
        float v = fmaxf(acc[mt][nt][r] + bv, 0.f);
        bf16 h = f2bf(v);
        ph_out[(size_t)m * D_ + n] = h;
        pl_out[(size_t)m * D_ + n] = f2bf(v - bf2f(h));
      }
    }
  }
}

// ---------------- K2: fused flash attention, split precision ----------------
__global__ __launch_bounds__(256, 1) void attn_kernel(const bf16* __restrict__ ph,
                                                      const bf16* __restrict__ pl,
                                                      const bf16* __restrict__ xT,
                                                      const int* __restrict__ xmask,
                                                      float* __restrict__ out) {
  const int b = blockIdx.y;
  const int i0 = blockIdx.x << 5;
  const int tid = threadIdx.x;
  const int wave = tid >> 6, lane = tid & 63;
  const int quad = lane >> 4, l16 = lane & 15;
  const int nbase = wave << 8;

  __shared__ bf16 Qh[32 * 1032];
  __shared__ bf16 Ql[32 * 1032];
  __shared__ float Ss[32 * 68];
  __shared__ bf16 Psh[32 * 72];
  __shared__ bf16 Psl[32 * 72];
  __shared__ float m_s[32], l_s[32], fac_s[32];

  const bf16* Qgh = ph + ((size_t)(b * L_ + i0)) * D_;
  const bf16* Qgl = pl + ((size_t)(b * L_ + i0)) * D_;
#pragma unroll 4
  for (int idx = tid; idx < 32 * 128; idx += 256) {
    const int r = idx >> 7, c = (idx & 127) << 3;
    *(float4*)&Qh[r * 1032 + c] = *(const float4*)&Qgh[(size_t)r * D_ + c];
    *(float4*)&Ql[r * 1032 + c] = *(const float4*)&Qgl[(size_t)r * D_ + c];
  }
  if (tid < 32) { m_s[tid] = NEGF; l_s[tid] = 0.f; }

  f32x4 acc[2][16];
#pragma unroll
  for (int mt = 0; mt < 2; ++mt)
#pragma unroll
    for (int nt = 0; nt < 16; ++nt) acc[mt][nt] = (f32x4){0.f, 0.f, 0.f, 0.f};

  __syncthreads();

  const bf16* Xg = xT + (size_t)b * D_ * L_;

  for (int jt = 0; jt < 32; ++jt) {
    const int j0 = jt << 6;
    const int jglob = j0 + (wave << 4) + l16;

    // ---- Phase A: S = Q K^T, 3-term split, 4 independent acc chains ----
    f32x4 sa0 = {0.f,0.f,0.f,0.f}, sb0 = {0.f,0.f,0.f,0.f};
    f32x4 sa1 = {0.f,0.f,0.f,0.f}, sb1 = {0.f,0.f,0.f,0.f};
    const bf16* Krh = ph + (size_t)(b * L_ + jglob) * D_;
    const bf16* Krl = pl + (size_t)(b * L_ + jglob) * D_;
#pragma unroll 4
    for (int kc = 0; kc < D_; kc += 32) {
      bf16x8 kh = *(const bf16x8*)&Krh[kc + quad * 8];
      bf16x8 kl = *(const bf16x8*)&Krl[kc + quad * 8];
      bf16x8 qh0 = *(const bf16x8*)&Qh[l16 * 1032 + kc + quad * 8];
      bf16x8 qh1 = *(const bf16x8*)&Qh[(16 + l16) * 1032 + kc + quad * 8];
      bf16x8 ql0 = *(const bf16x8*)&Ql[l16 * 1032 + kc + quad * 8];
      bf16x8 ql1 = *(const bf16x8*)&Ql[(16 + l16) * 1032 + kc + quad * 8];
      sa0 = MFMA16(qh0, kh, sa0);
      sa1 = MFMA16(qh1, kh, sa1);
      sb0 = MFMA16(qh0, kl, sb0);
      sb1 = MFMA16(qh1, kl, sb1);
      sb0 = MFMA16(ql0, kh, sb0);
      sb1 = MFMA16(ql1, kh, sb1);
    }

    // ---- Phase B: diag-zero, padding mask, stash S ----
    const bool masked = (xmask[b * L_ + jglob] != 0);
#pragma unroll
    for (int mt = 0; mt < 2; ++mt) {
#pragma unroll
      for (int r = 0; r < 4; ++r) {
        const int irow = (mt << 4) + (quad << 2) + r;
        float v = mt ? (sa1[r] + sb1[r]) : (sa0[r] + sb0[r]);
        if (i0 + irow == jglob) v = 0.f;
        if (masked) v = NEGF;
        Ss[irow * 68 + (wave << 4) + l16] = v;
      }
    }
    __syncthreads();

    // ---- Phase C: online softmax (8 threads/row), split P ----
    {
      const int row = tid >> 3, part = tid & 7;
      const float* srow = &Ss[row * 68 + (part << 3)];
      const float4 sA = *(const float4*)srow;
      const float4 sB = *(const float4*)(srow + 4);
      float mx = fmaxf(fmaxf(fmaxf(sA.x, sA.y), fmaxf(sA.z, sA.w)),
                       fmaxf(fmaxf(sB.x, sB.y), fmaxf(sB.z, sB.w)));
      mx = fmaxf(mx, __shfl_xor(mx, 1));
      mx = fmaxf(mx, __shfl_xor(mx, 2));
      mx = fmaxf(mx, __shfl_xor(mx, 4));
      const float m_old = m_s[row];
      const float m_new = fmaxf(m_old, mx);
      float p[8];
      p[0] = __expf(sA.x - m_new); p[1] = __expf(sA.y - m_new);
      p[2] = __expf(sA.z - m_new); p[3] = __expf(sA.w - m_new);
      p[4] = __expf(sB.x - m_new); p[5] = __expf(sB.y - m_new);
      p[6] = __expf(sB.z - m_new); p[7] = __expf(sB.w - m_new);
      float sum = ((p[0] + p[1]) + (p[2] + p[3])) + ((p[4] + p[5]) + (p[6] + p[7]));
      sum += __shfl_xor(sum, 1);
      sum += __shfl_xor(sum, 2);
      sum += __shfl_xor(sum, 4);
      const float fac = __expf(m_old - m_new);
      if (part == 0) {
        m_s[row] = m_new;
        l_s[row] = l_s[row] * fac + sum;
        fac_s[row] = fac;
      }
      union { bf16 h[8]; uint4 u; } hp, lp;
#pragma unroll
      for (int i = 0; i < 8; ++i) {
        hp.h[i] = f2bf(p[i]);
        lp.h[i] = f2bf(p[i] - bf2f(hp.h[i]));
      }
      *(uint4*)&Psh[row * 72 + (part << 3)] = hp.u;
      *(uint4*)&Psl[row * 72 + (part << 3)] = lp.u;
    }
    __syncthreads();

    // ---- Phase D: rescale O, then O += (Ph+Pl) @ x_hi ----
    float facr[2][4];
#pragma unroll
    for (int mt = 0; mt < 2; ++mt)
#pragma unroll
      for (int r = 0; r < 4; ++r) facr[mt][r] = fac_s[(mt << 4) + (quad << 2) + r];
#pragma unroll
    for (int mt = 0; mt < 2; ++mt)
#pragma unroll
      for (int nt = 0; nt < 16; ++nt)
#pragma unroll
        for (int r = 0; r < 4; ++r) acc[mt][nt][r] *= facr[mt][r];

    bf16x8 pah[2][2], pal[2][2];
#pragma unroll
    for (int mt = 0; mt < 2; ++mt)
#pragma unroll
      for (int kt = 0; kt < 2; ++kt) {
        pah[mt][kt] = *(const bf16x8*)&Psh[((mt << 4) + l16) * 72 + (kt << 5) + quad * 8];
        pal[mt][kt] = *(const bf16x8*)&Psl[((mt << 4) + l16) * 72 + (kt << 5) + quad * 8];
      }

#pragma unroll 4
    for (int nt = 0; nt < 16; ++nt) {
      const bf16* Xrow = Xg + (size_t)(nbase + (nt << 4) + l16) * L_ + j0;
      bf16x8 xb0 = *(const bf16x8*)&Xrow[quad * 8];
      bf16x8 xb1 = *(const bf16x8*)&Xrow[32 + quad * 8];
      acc[0][nt] = MFMA16(pah[0][0], xb0, acc[0][nt]);
      acc[0][nt] = MFMA16(pah[0][1], xb1, acc[0][nt]);
      acc[0][nt] = MFMA16(pal[0][0], xb0, acc[0][nt]);
      acc[0][nt] = MFMA16(pal[0][1], xb1, acc[0][nt]);
      acc[1][nt] = MFMA16(pah[1][0], xb0, acc[1][nt]);
      acc[1][nt] = MFMA16(pah[1][1], xb1, acc[1][nt]);
      acc[1][nt] = MFMA16(pal[1][0], xb0, acc[1][nt]);
      acc[1][nt] = MFMA16(pal[1][1], xb1, acc[1][nt]);
    }
  }

  // ---- epilogue: out = O / l (fp32 store) ----
  float inv[2][4];
#pragma unroll
  for (int mt = 0; mt < 2; ++mt)
#pragma unroll
    for (int r = 0; r < 4; ++r) inv[mt][r] = 1.0f / l_s[(mt << 4) + (quad << 2) + r];
#pragma unroll
  for (int mt = 0; mt < 2; ++mt) {
#pragma unroll
    for (int nt = 0; nt < 16; ++nt) {
#pragma unroll
      for (int r = 0; r < 4; ++r) {
        const int row = i0 + (mt << 4) + (quad << 2) + r;
        const int col = nbase + (nt << 4) + l16;
        out[((size_t)(b * L_ + row)) * D_ + col] = acc[mt][nt][r] * inv[mt][r];
      }
    }
  }
}

extern "C" void kernel_launch(void* const* d_in, const int* in_sizes, int n_in,
                              void* d_out, int out_size, void* d_ws, size_t ws_size,
                              hipStream_t stream) {
  const float* x = (const float*)d_in[0];
  const int* xmask = (const int*)d_in[1];
  const float* W = (const float*)d_in[2];
  const float* bias = (const float*)d_in[3];
  float* out = (float*)d_out;

  const size_t elems = (size_t)B_ * L_ * D_;
  if (ws_size < 3 * elems * sizeof(bf16)) return;  // need 96 MiB scratch
  bf16* ph = (bf16*)d_ws;
  bf16* pl = ph + elems;
  bf16* xT = pl + elems;

  transpose_kernel<<<dim3(L_ / 32, D_ / 32, B_), 256, 0, stream>>>(x, xT);
  proj_kernel<<<dim3((B_ * L_) / 64, D_ / 64), 256, 0, stream>>>(x, W, bias, ph, pl);
  attn_kernel<<<dim3(L_ / 32, B_), 256, 0, stream>>>(ph, pl, xT, xmask, out);
}

// Round 3
// 1698.467 us; speedup vs baseline: 1.1574x; 1.1574x over previous
//
#include <hip/hip_runtime.h>
#include <hip/hip_bf16.h>

// R3: single-term f16 pipeline (f16 rounding err ~5e-4 -> deltaS ~0.01, well
// under the 0.108 threshold). Halves LDS (Q tile 66 KB) -> 2 blocks/CU in attn,
// cuts MFMA count 3x (QK^T) / 2x (PV). ws: [proj f16][xT f16] = 67 MB.

typedef _Float16 f16;
typedef float f32x4 __attribute__((ext_vector_type(4)));
typedef _Float16 f16x8 __attribute__((ext_vector_type(8)));

#define MFMAH(A, B, C) __builtin_amdgcn_mfma_f32_16x16x32_f16((A), (B), (C), 0, 0, 0)

static constexpr int B_ = 8;
static constexpr int L_ = 2048;
static constexpr int D_ = 1024;
#define NEGF (-1e30f)

// ---------------- K0: transpose x[B][L][D] fp32 -> xT[B][D][L] f16 ----------------
__global__ __launch_bounds__(256) void transpose_kernel(const float* __restrict__ x,
                                                        f16* __restrict__ xT) {
  __shared__ f16 t[32][40];
  const int b = blockIdx.z;
  const int j0 = blockIdx.x << 5, d0 = blockIdx.y << 5;
  const int tid = threadIdx.x;
  const int r = tid >> 3, c = (tid & 7) << 2;
  float4 v = *(const float4*)&x[((size_t)(b * L_ + j0 + r)) * D_ + d0 + c];
  t[r][c + 0] = (f16)v.x; t[r][c + 1] = (f16)v.y;
  t[r][c + 2] = (f16)v.z; t[r][c + 3] = (f16)v.w;
  __syncthreads();
  union { f16 h[4]; uint2 u; } o;
  o.h[0] = t[c + 0][r]; o.h[1] = t[c + 1][r];
  o.h[2] = t[c + 2][r]; o.h[3] = t[c + 3][r];
  *(uint2*)&xT[((size_t)(b * D_ + d0 + r)) * L_ + j0 + c] = o.u;
}

// ---------------- K1: proj = relu(x @ W^T + b), f16 GEMM 64x64 tile ----------------
__global__ __launch_bounds__(256, 2) void proj_kernel(const float* __restrict__ x,
                                                      const float* __restrict__ W,
                                                      const float* __restrict__ bias,
                                                      f16* __restrict__ proj) {
  const int m0 = blockIdx.x << 6, n0 = blockIdx.y << 6;
  __shared__ f16 As[64 * 40], Bs[64 * 40];
  const int tid = threadIdx.x;
  const int wave = tid >> 6, lane = tid & 63;
  const int wr = wave >> 1, wc = wave & 1;
  const int quad = lane >> 4, l16 = lane & 15;
  const int srow = tid >> 2, scol = (tid & 3) << 3;

  f32x4 acc[2][2];
#pragma unroll
  for (int mt = 0; mt < 2; ++mt)
#pragma unroll
    for (int nt = 0; nt < 2; ++nt) acc[mt][nt] = (f32x4){0.f, 0.f, 0.f, 0.f};

  const float* xrow = &x[(size_t)(m0 + srow) * D_];
  const float* wrow = &W[(size_t)(n0 + srow) * D_];

  for (int kc = 0; kc < D_; kc += 32) {
    {
      float4 va = *(const float4*)&xrow[kc + scol];
      float4 vb = *(const float4*)&xrow[kc + scol + 4];
      union { f16 h[8]; uint4 u; } H;
      H.h[0] = (f16)va.x; H.h[1] = (f16)va.y; H.h[2] = (f16)va.z; H.h[3] = (f16)va.w;
      H.h[4] = (f16)vb.x; H.h[5] = (f16)vb.y; H.h[6] = (f16)vb.z; H.h[7] = (f16)vb.w;
      *(uint4*)&As[srow * 40 + scol] = H.u;
      float4 wa = *(const float4*)&wrow[kc + scol];
      float4 wb = *(const float4*)&wrow[kc + scol + 4];
      H.h[0] = (f16)wa.x; H.h[1] = (f16)wa.y; H.h[2] = (f16)wa.z; H.h[3] = (f16)wa.w;
      H.h[4] = (f16)wb.x; H.h[5] = (f16)wb.y; H.h[6] = (f16)wb.z; H.h[7] = (f16)wb.w;
      *(uint4*)&Bs[srow * 40 + scol] = H.u;
    }
    __syncthreads();
    f16x8 a0 = *(const f16x8*)&As[(wr * 32 + l16) * 40 + quad * 8];
    f16x8 a1 = *(const f16x8*)&As[(wr * 32 + 16 + l16) * 40 + quad * 8];
    f16x8 b0 = *(const f16x8*)&Bs[(wc * 32 + l16) * 40 + quad * 8];
    f16x8 b1 = *(const f16x8*)&Bs[(wc * 32 + 16 + l16) * 40 + quad * 8];
    acc[0][0] = MFMAH(a0, b0, acc[0][0]);
    acc[0][1] = MFMAH(a0, b1, acc[0][1]);
    acc[1][0] = MFMAH(a1, b0, acc[1][0]);
    acc[1][1] = MFMAH(a1, b1, acc[1][1]);
    __syncthreads();
  }
#pragma unroll
  for (int mt = 0; mt < 2; ++mt) {
#pragma unroll
    for (int nt = 0; nt < 2; ++nt) {
      const int n = n0 + wc * 32 + nt * 16 + l16;
      const float bv = bias[n];
#pragma unroll
      for (int r = 0; r < 4; ++r) {
        const int m = m0 + wr * 32 + mt * 16 + quad * 4 + r;
        proj[(size_t)m * D_ + n] = (f16)fmaxf(acc[mt][nt][r] + bv, 0.f);
      }
    }
  }
}

// ---------------- K2: fused flash attention, f16 ----------------
// LDS = 66048 (Qs) + 9728 (Ss) + 4608 (Ps) + 384 = 78.9 KB -> 2 blocks/CU.
__global__ __launch_bounds__(256, 2) void attn_kernel(const f16* __restrict__ proj,
                                                      const f16* __restrict__ xT,
                                                      const int* __restrict__ xmask,
                                                      float* __restrict__ out) {
  const int b = blockIdx.y;
  const int i0 = blockIdx.x << 5;
  const int tid = threadIdx.x;
  const int wave = tid >> 6, lane = tid & 63;
  const int quad = lane >> 4, l16 = lane & 15;
  const int nbase = wave << 8;

  __shared__ f16 Qs[32 * 1032];    // stride 1032: 2-way (free) on frag reads
  __shared__ float Ss[32 * 76];    // stride 76: breaks the 4-way S-write conflict
  __shared__ f16 Ps[32 * 72];      // stride 72: 16B-aligned rows
  __shared__ float m_s[32], l_s[32], fac_s[32];

  const f16* Qg = proj + ((size_t)(b * L_ + i0)) * D_;
#pragma unroll 4
  for (int idx = tid; idx < 32 * 128; idx += 256) {
    const int r = idx >> 7, c = (idx & 127) << 3;
    *(float4*)&Qs[r * 1032 + c] = *(const float4*)&Qg[(size_t)r * D_ + c];
  }
  if (tid < 32) { m_s[tid] = NEGF; l_s[tid] = 0.f; }

  f32x4 acc[2][16];
#pragma unroll
  for (int mt = 0; mt < 2; ++mt)
#pragma unroll
    for (int nt = 0; nt < 16; ++nt) acc[mt][nt] = (f32x4){0.f, 0.f, 0.f, 0.f};

  __syncthreads();

  const f16* Xg = xT + (size_t)b * D_ * L_;

  for (int jt = 0; jt < 32; ++jt) {
    const int j0 = jt << 6;
    const int jglob = j0 + (wave << 4) + l16;
    const bool masked = (xmask[b * L_ + jglob] != 0);

    // ---- Phase A: S = Q K^T, 4 independent acc chains ----
    f32x4 s0a = {0.f,0.f,0.f,0.f}, s0b = {0.f,0.f,0.f,0.f};
    f32x4 s1a = {0.f,0.f,0.f,0.f}, s1b = {0.f,0.f,0.f,0.f};
    const f16* Krow = proj + (size_t)(b * L_ + jglob) * D_;
#pragma unroll 4
    for (int kc = 0; kc < D_; kc += 64) {
      f16x8 k0 = *(const f16x8*)&Krow[kc + quad * 8];
      f16x8 k1 = *(const f16x8*)&Krow[kc + 32 + quad * 8];
      f16x8 qa0 = *(const f16x8*)&Qs[l16 * 1032 + kc + quad * 8];
      f16x8 qa1 = *(const f16x8*)&Qs[(16 + l16) * 1032 + kc + quad * 8];
      f16x8 qb0 = *(const f16x8*)&Qs[l16 * 1032 + kc + 32 + quad * 8];
      f16x8 qb1 = *(const f16x8*)&Qs[(16 + l16) * 1032 + kc + 32 + quad * 8];
      s0a = MFMAH(qa0, k0, s0a);
      s1a = MFMAH(qa1, k0, s1a);
      s0b = MFMAH(qb0, k1, s0b);
      s1b = MFMAH(qb1, k1, s1b);
    }

    // ---- Phase B: diag-zero, padding mask, stash S ----
#pragma unroll
    for (int mt = 0; mt < 2; ++mt) {
#pragma unroll
      for (int r = 0; r < 4; ++r) {
        const int irow = (mt << 4) + (quad << 2) + r;
        float v = mt ? (s1a[r] + s1b[r]) : (s0a[r] + s0b[r]);
        if (i0 + irow == jglob) v = 0.f;
        if (masked) v = NEGF;
        Ss[irow * 76 + (wave << 4) + l16] = v;
      }
    }
    __syncthreads();

    // ---- Phase C: online softmax (8 threads/row) ----
    {
      const int row = tid >> 3, part = tid & 7;
      const float* srow = &Ss[row * 76 + (part << 3)];
      const float4 sA = *(const float4*)srow;
      const float4 sB = *(const float4*)(srow + 4);
      float mx = fmaxf(fmaxf(fmaxf(sA.x, sA.y), fmaxf(sA.z, sA.w)),
                       fmaxf(fmaxf(sB.x, sB.y), fmaxf(sB.z, sB.w)));
      mx = fmaxf(mx, __shfl_xor(mx, 1));
      mx = fmaxf(mx, __shfl_xor(mx, 2));
      mx = fmaxf(mx, __shfl_xor(mx, 4));
      const float m_old = m_s[row];
      const float m_new = fmaxf(m_old, mx);
      float p[8];
      p[0] = __expf(sA.x - m_new); p[1] = __expf(sA.y - m_new);
      p[2] = __expf(sA.z - m_new); p[3] = __expf(sA.w - m_new);
      p[4] = __expf(sB.x - m_new); p[5] = __expf(sB.y - m_new);
      p[6] = __expf(sB.z - m_new); p[7] = __expf(sB.w - m_new);
      float sum = ((p[0] + p[1]) + (p[2] + p[3])) + ((p[4] + p[5]) + (p[6] + p[7]));
      sum += __shfl_xor(sum, 1);
      sum += __shfl_xor(sum, 2);
      sum += __shfl_xor(sum, 4);
      const float fac = __expf(m_old - m_new);
      if (part == 0) {
        m_s[row] = m_new;
        l_s[row] = l_s[row] * fac + sum;
        fac_s[row] = fac;
      }
      union { f16 h[8]; uint4 u; } hp;
#pragma unroll
      for (int i = 0; i < 8; ++i) hp.h[i] = (f16)p[i];
      *(uint4*)&Ps[row * 72 + (part << 3)] = hp.u;
    }
    __syncthreads();

    // ---- Phase D: rescale O, then O += P @ X ----
    float facr[2][4];
#pragma unroll
    for (int mt = 0; mt < 2; ++mt)
#pragma unroll
      for (int r = 0; r < 4; ++r) facr[mt][r] = fac_s[(mt << 4) + (quad << 2) + r];
#pragma unroll
    for (int mt = 0; mt < 2; ++mt)
#pragma unroll
      for (int nt = 0; nt < 16; ++nt)
#pragma unroll
        for (int r = 0; r < 4; ++r) acc[mt][nt][r] *= facr[mt][r];

    f16x8 pa[2][2];
#pragma unroll
    for (int mt = 0; mt < 2; ++mt)
#pragma unroll
      for (int kt = 0; kt < 2; ++kt)
        pa[mt][kt] = *(const f16x8*)&Ps[((mt << 4) + l16) * 72 + (kt << 5) + quad * 8];

#pragma unroll 4
    for (int nt = 0; nt < 16; ++nt) {
      const f16* Xrow = Xg + (size_t)(nbase + (nt << 4) + l16) * L_ + j0;
      f16x8 xb0 = *(const f16x8*)&Xrow[quad * 8];
      f16x8 xb1 = *(const f16x8*)&Xrow[32 + quad * 8];
      acc[0][nt] = MFMAH(pa[0][0], xb0, acc[0][nt]);
      acc[0][nt] = MFMAH(pa[0][1], xb1, acc[0][nt]);
      acc[1][nt] = MFMAH(pa[1][0], xb0, acc[1][nt]);
      acc[1][nt] = MFMAH(pa[1][1], xb1, acc[1][nt]);
    }
  }

  // ---- epilogue: out = O / l ----
  float inv[2][4];
#pragma unroll
  for (int mt = 0; mt < 2; ++mt)
#pragma unroll
    for (int r = 0; r < 4; ++r) inv[mt][r] = 1.0f / l_s[(mt << 4) + (quad << 2) + r];
#pragma unroll
  for (int mt = 0; mt < 2; ++mt) {
#pragma unroll
    for (int nt = 0; nt < 16; ++nt) {
#pragma unroll
      for (int r = 0; r < 4; ++r) {
        const int row = i0 + (mt << 4) + (quad << 2) + r;
        const int col = nbase + (nt << 4) + l16;
        out[((size_t)(b * L_ + row)) * D_ + col] = acc[mt][nt][r] * inv[mt][r];
      }
    }
  }
}

extern "C" void kernel_launch(void* const* d_in, const int* in_sizes, int n_in,
                              void* d_out, int out_size, void* d_ws, size_t ws_size,
                              hipStream_t stream) {
  const float* x = (const float*)d_in[0];
  const int* xmask = (const int*)d_in[1];
  const float* W = (const float*)d_in[2];
  const float* bias = (const float*)d_in[3];
  float* out = (float*)d_out;

  const size_t elems = (size_t)B_ * L_ * D_;
  if (ws_size < 2 * elems * sizeof(f16)) return;
  f16* proj = (f16*)d_ws;
  f16* xT = proj + elems;

  transpose_kernel<<<dim3(L_ / 32, D_ / 32, B_), 256, 0, stream>>>(x, xT);
  proj_kernel<<<dim3((B_ * L_) / 64, D_ / 64), 256, 0, stream>>>(x, W, bias, proj);
  attn_kernel<<<dim3(L_ / 32, B_), 256, 0, stream>>>(proj, xT, xmask, out);
}

// Round 4
// 723.292 us; speedup vs baseline: 2.7179x; 2.3482x over previous
//
#include <hip/hip_runtime.h>
#include <hip/hip_bf16.h>

// R4: same f16 pipeline as R3, but with the O-accumulator forced register-resident.
// R3's "#pragma unroll 4" on Phase D's nt-loop left a runtime index into acc[][],
// demoting it to scratch: 4.3 GB/dispatch of spill writes (WRITE_SIZE counter) and
// VGPR_Count=92. Full unroll => acc lives in VGPRs/AGPRs (~200 regs, cap 256 at
// 2 waves/SIMD).

typedef _Float16 f16;
typedef float f32x4 __attribute__((ext_vector_type(4)));
typedef _Float16 f16x8 __attribute__((ext_vector_type(8)));

#define MFMAH(A, B, C) __builtin_amdgcn_mfma_f32_16x16x32_f16((A), (B), (C), 0, 0, 0)

static constexpr int B_ = 8;
static constexpr int L_ = 2048;
static constexpr int D_ = 1024;
#define NEGF (-1e30f)

// ---------------- K0: transpose x[B][L][D] fp32 -> xT[B][D][L] f16 ----------------
__global__ __launch_bounds__(256) void transpose_kernel(const float* __restrict__ x,
                                                        f16* __restrict__ xT) {
  __shared__ f16 t[32][40];
  const int b = blockIdx.z;
  const int j0 = blockIdx.x << 5, d0 = blockIdx.y << 5;
  const int tid = threadIdx.x;
  const int r = tid >> 3, c = (tid & 7) << 2;
  float4 v = *(const float4*)&x[((size_t)(b * L_ + j0 + r)) * D_ + d0 + c];
  t[r][c + 0] = (f16)v.x; t[r][c + 1] = (f16)v.y;
  t[r][c + 2] = (f16)v.z; t[r][c + 3] = (f16)v.w;
  __syncthreads();
  union { f16 h[4]; uint2 u; } o;
  o.h[0] = t[c + 0][r]; o.h[1] = t[c + 1][r];
  o.h[2] = t[c + 2][r]; o.h[3] = t[c + 3][r];
  *(uint2*)&xT[((size_t)(b * D_ + d0 + r)) * L_ + j0 + c] = o.u;
}

// ---------------- K1: proj = relu(x @ W^T + b), f16 GEMM 64x64 tile ----------------
__global__ __launch_bounds__(256, 2) void proj_kernel(const float* __restrict__ x,
                                                      const float* __restrict__ W,
                                                      const float* __restrict__ bias,
                                                      f16* __restrict__ proj) {
  const int m0 = blockIdx.x << 6, n0 = blockIdx.y << 6;
  __shared__ f16 As[64 * 40], Bs[64 * 40];
  const int tid = threadIdx.x;
  const int wave = tid >> 6, lane = tid & 63;
  const int wr = wave >> 1, wc = wave & 1;
  const int quad = lane >> 4, l16 = lane & 15;
  const int srow = tid >> 2, scol = (tid & 3) << 3;

  f32x4 acc[2][2];
#pragma unroll
  for (int mt = 0; mt < 2; ++mt)
#pragma unroll
    for (int nt = 0; nt < 2; ++nt) acc[mt][nt] = (f32x4){0.f, 0.f, 0.f, 0.f};

  const float* xrow = &x[(size_t)(m0 + srow) * D_];
  const float* wrow = &W[(size_t)(n0 + srow) * D_];

  for (int kc = 0; kc < D_; kc += 32) {
    {
      float4 va = *(const float4*)&xrow[kc + scol];
      float4 vb = *(const float4*)&xrow[kc + scol + 4];
      union { f16 h[8]; uint4 u; } H;
      H.h[0] = (f16)va.x; H.h[1] = (f16)va.y; H.h[2] = (f16)va.z; H.h[3] = (f16)va.w;
      H.h[4] = (f16)vb.x; H.h[5] = (f16)vb.y; H.h[6] = (f16)vb.z; H.h[7] = (f16)vb.w;
      *(uint4*)&As[srow * 40 + scol] = H.u;
      float4 wa = *(const float4*)&wrow[kc + scol];
      float4 wb = *(const float4*)&wrow[kc + scol + 4];
      H.h[0] = (f16)wa.x; H.h[1] = (f16)wa.y; H.h[2] = (f16)wa.z; H.h[3] = (f16)wa.w;
      H.h[4] = (f16)wb.x; H.h[5] = (f16)wb.y; H.h[6] = (f16)wb.z; H.h[7] = (f16)wb.w;
      *(uint4*)&Bs[srow * 40 + scol] = H.u;
    }
    __syncthreads();
    f16x8 a0 = *(const f16x8*)&As[(wr * 32 + l16) * 40 + quad * 8];
    f16x8 a1 = *(const f16x8*)&As[(wr * 32 + 16 + l16) * 40 + quad * 8];
    f16x8 b0 = *(const f16x8*)&Bs[(wc * 32 + l16) * 40 + quad * 8];
    f16x8 b1 = *(const f16x8*)&Bs[(wc * 32 + 16 + l16) * 40 + quad * 8];
    acc[0][0] = MFMAH(a0, b0, acc[0][0]);
    acc[0][1] = MFMAH(a0, b1, acc[0][1]);
    acc[1][0] = MFMAH(a1, b0, acc[1][0]);
    acc[1][1] = MFMAH(a1, b1, acc[1][1]);
    __syncthreads();
  }
#pragma unroll
  for (int mt = 0; mt < 2; ++mt) {
#pragma unroll
    for (int nt = 0; nt < 2; ++nt) {
      const int n = n0 + wc * 32 + nt * 16 + l16;
      const float bv = bias[n];
#pragma unroll
      for (int r = 0; r < 4; ++r) {
        const int m = m0 + wr * 32 + mt * 16 + quad * 4 + r;
        proj[(size_t)m * D_ + n] = (f16)fmaxf(acc[mt][nt][r] + bv, 0.f);
      }
    }
  }
}

// ---------------- K2: fused flash attention, f16, register-resident O ----------------
// LDS = 66048 (Qs) + 9728 (Ss) + 4608 (Ps) + 384 = 78.9 KB -> 2 blocks/CU.
__global__ __launch_bounds__(256, 2) void attn_kernel(const f16* __restrict__ proj,
                                                      const f16* __restrict__ xT,
                                                      const int* __restrict__ xmask,
                                                      float* __restrict__ out) {
  const int b = blockIdx.y;
  const int i0 = blockIdx.x << 5;
  const int tid = threadIdx.x;
  const int wave = tid >> 6, lane = tid & 63;
  const int quad = lane >> 4, l16 = lane & 15;
  const int nbase = wave << 8;

  __shared__ f16 Qs[32 * 1032];
  __shared__ float Ss[32 * 76];
  __shared__ f16 Ps[32 * 72];
  __shared__ float m_s[32], l_s[32], fac_s[32];

  const f16* Qg = proj + ((size_t)(b * L_ + i0)) * D_;
#pragma unroll 4
  for (int idx = tid; idx < 32 * 128; idx += 256) {
    const int r = idx >> 7, c = (idx & 127) << 3;
    *(float4*)&Qs[r * 1032 + c] = *(const float4*)&Qg[(size_t)r * D_ + c];
  }
  if (tid < 32) { m_s[tid] = NEGF; l_s[tid] = 0.f; }

  f32x4 acc[2][16];
#pragma unroll
  for (int mt = 0; mt < 2; ++mt)
#pragma unroll
    for (int nt = 0; nt < 16; ++nt) acc[mt][nt] = (f32x4){0.f, 0.f, 0.f, 0.f};

  __syncthreads();

  const f16* Xg = xT + (size_t)b * D_ * L_;

  for (int jt = 0; jt < 32; ++jt) {
    const int j0 = jt << 6;
    const int jglob = j0 + (wave << 4) + l16;
    const bool masked = (xmask[b * L_ + jglob] != 0);

    // ---- Phase A: S = Q K^T, 4 independent acc chains ----
    f32x4 s0a = {0.f,0.f,0.f,0.f}, s0b = {0.f,0.f,0.f,0.f};
    f32x4 s1a = {0.f,0.f,0.f,0.f}, s1b = {0.f,0.f,0.f,0.f};
    const f16* Krow = proj + (size_t)(b * L_ + jglob) * D_;
#pragma unroll 4
    for (int kc = 0; kc < D_; kc += 64) {
      f16x8 k0 = *(const f16x8*)&Krow[kc + quad * 8];
      f16x8 k1 = *(const f16x8*)&Krow[kc + 32 + quad * 8];
      f16x8 qa0 = *(const f16x8*)&Qs[l16 * 1032 + kc + quad * 8];
      f16x8 qa1 = *(const f16x8*)&Qs[(16 + l16) * 1032 + kc + quad * 8];
      f16x8 qb0 = *(const f16x8*)&Qs[l16 * 1032 + kc + 32 + quad * 8];
      f16x8 qb1 = *(const f16x8*)&Qs[(16 + l16) * 1032 + kc + 32 + quad * 8];
      s0a = MFMAH(qa0, k0, s0a);
      s1a = MFMAH(qa1, k0, s1a);
      s0b = MFMAH(qb0, k1, s0b);
      s1b = MFMAH(qb1, k1, s1b);
    }

    // ---- Phase B: diag-zero, padding mask, stash S ----
#pragma unroll
    for (int mt = 0; mt < 2; ++mt) {
#pragma unroll
      for (int r = 0; r < 4; ++r) {
        const int irow = (mt << 4) + (quad << 2) + r;
        float v = mt ? (s1a[r] + s1b[r]) : (s0a[r] + s0b[r]);
        if (i0 + irow == jglob) v = 0.f;
        if (masked) v = NEGF;
        Ss[irow * 76 + (wave << 4) + l16] = v;
      }
    }
    __syncthreads();

    // ---- Phase C: online softmax (8 threads/row) ----
    {
      const int row = tid >> 3, part = tid & 7;
      const float* srow = &Ss[row * 76 + (part << 3)];
      const float4 sA = *(const float4*)srow;
      const float4 sB = *(const float4*)(srow + 4);
      float mx = fmaxf(fmaxf(fmaxf(sA.x, sA.y), fmaxf(sA.z, sA.w)),
                       fmaxf(fmaxf(sB.x, sB.y), fmaxf(sB.z, sB.w)));
      mx = fmaxf(mx, __shfl_xor(mx, 1));
      mx = fmaxf(mx, __shfl_xor(mx, 2));
      mx = fmaxf(mx, __shfl_xor(mx, 4));
      const float m_old = m_s[row];
      const float m_new = fmaxf(m_old, mx);
      float p[8];
      p[0] = __expf(sA.x - m_new); p[1] = __expf(sA.y - m_new);
      p[2] = __expf(sA.z - m_new); p[3] = __expf(sA.w - m_new);
      p[4] = __expf(sB.x - m_new); p[5] = __expf(sB.y - m_new);
      p[6] = __expf(sB.z - m_new); p[7] = __expf(sB.w - m_new);
      float sum = ((p[0] + p[1]) + (p[2] + p[3])) + ((p[4] + p[5]) + (p[6] + p[7]));
      sum += __shfl_xor(sum, 1);
      sum += __shfl_xor(sum, 2);
      sum += __shfl_xor(sum, 4);
      const float fac = __expf(m_old - m_new);
      if (part == 0) {
        m_s[row] = m_new;
        l_s[row] = l_s[row] * fac + sum;
        fac_s[row] = fac;
      }
      union { f16 h[8]; uint4 u; } hp;
#pragma unroll
      for (int i = 0; i < 8; ++i) hp.h[i] = (f16)p[i];
      *(uint4*)&Ps[row * 72 + (part << 3)] = hp.u;
    }
    __syncthreads();

    // ---- Phase D: rescale O, then O += P @ X (FULLY unrolled: acc stays in regs) ----
    float facr[2][4];
#pragma unroll
    for (int mt = 0; mt < 2; ++mt)
#pragma unroll
      for (int r = 0; r < 4; ++r) facr[mt][r] = fac_s[(mt << 4) + (quad << 2) + r];
#pragma unroll
    for (int mt = 0; mt < 2; ++mt)
#pragma unroll
      for (int nt = 0; nt < 16; ++nt)
#pragma unroll
        for (int r = 0; r < 4; ++r) acc[mt][nt][r] *= facr[mt][r];

    f16x8 pa[2][2];
#pragma unroll
    for (int mt = 0; mt < 2; ++mt)
#pragma unroll
      for (int kt = 0; kt < 2; ++kt)
        pa[mt][kt] = *(const f16x8*)&Ps[((mt << 4) + l16) * 72 + (kt << 5) + quad * 8];

#pragma unroll
    for (int nt = 0; nt < 16; ++nt) {
      const f16* Xrow = Xg + (size_t)(nbase + (nt << 4) + l16) * L_ + j0;
      f16x8 xb0 = *(const f16x8*)&Xrow[quad * 8];
      f16x8 xb1 = *(const f16x8*)&Xrow[32 + quad * 8];
      acc[0][nt] = MFMAH(pa[0][0], xb0, acc[0][nt]);
      acc[0][nt] = MFMAH(pa[0][1], xb1, acc[0][nt]);
      acc[1][nt] = MFMAH(pa[1][0], xb0, acc[1][nt]);
      acc[1][nt] = MFMAH(pa[1][1], xb1, acc[1][nt]);
    }
  }

  // ---- epilogue: out = O / l ----
  float inv[2][4];
#pragma unroll
  for (int mt = 0; mt < 2; ++mt)
#pragma unroll
    for (int r = 0; r < 4; ++r) inv[mt][r] = 1.0f / l_s[(mt << 4) + (quad << 2) + r];
#pragma unroll
  for (int mt = 0; mt < 2; ++mt) {
#pragma unroll
    for (int nt = 0; nt < 16; ++nt) {
#pragma unroll
      for (int r = 0; r < 4; ++r) {
        const int row = i0 + (mt << 4) + (quad << 2) + r;
        const int col = nbase + (nt << 4) + l16;
        out[((size_t)(b * L_ + row)) * D_ + col] = acc[mt][nt][r] * inv[mt][r];
      }
    }
  }
}

extern "C" void kernel_launch(void* const* d_in, const int* in_sizes, int n_in,
                              void* d_out, int out_size, void* d_ws, size_t ws_size,
                              hipStream_t stream) {
  const float* x = (const float*)d_in[0];
  const int* xmask = (const int*)d_in[1];
  const float* W = (const float*)d_in[2];
  const float* bias = (const float*)d_in[3];
  float* out = (float*)d_out;

  const size_t elems = (size_t)B_ * L_ * D_;
  if (ws_size < 2 * elems * sizeof(f16)) return;
  f16* proj = (f16*)d_ws;
  f16* xT = proj + elems;

  transpose_kernel<<<dim3(L_ / 32, D_ / 32, B_), 256, 0, stream>>>(x, xT);
  proj_kernel<<<dim3((B_ * L_) / 64, D_ / 64), 256, 0, stream>>>(x, W, bias, proj);
  attn_kernel<<<dim3(L_ / 32, B_), 256, 0, stream>>>(proj, xT, xmask, out);
}

// Round 5
// 709.973 us; speedup vs baseline: 2.7688x; 1.0188x over previous
//
#include <hip/hip_runtime.h>
#include <hip/hip_bf16.h>

// R5: R4 + (a) XCD-pinned batch swizzle: 1D grid, b = blockIdx%8 -> all 64 blocks
// of a batch on one XCD (round-robin dispatch heuristic), so the hot per-jt K/X
// tiles (~256 KB) stay L2-resident instead of thrashing to L3. (b) explicit
// 1-deep register pipelining of the K-row and X-row global loads so next-iter
// loads are in flight while current MFMAs execute.

typedef _Float16 f16;
typedef float f32x4 __attribute__((ext_vector_type(4)));
typedef _Float16 f16x8 __attribute__((ext_vector_type(8)));

#define MFMAH(A, B, C) __builtin_amdgcn_mfma_f32_16x16x32_f16((A), (B), (C), 0, 0, 0)

static constexpr int B_ = 8;
static constexpr int L_ = 2048;
static constexpr int D_ = 1024;
#define NEGF (-1e30f)

// ---------------- K0: transpose x[B][L][D] fp32 -> xT[B][D][L] f16 ----------------
__global__ __launch_bounds__(256) void transpose_kernel(const float* __restrict__ x,
                                                        f16* __restrict__ xT) {
  __shared__ f16 t[32][40];
  const int b = blockIdx.z;
  const int j0 = blockIdx.x << 5, d0 = blockIdx.y << 5;
  const int tid = threadIdx.x;
  const int r = tid >> 3, c = (tid & 7) << 2;
  float4 v = *(const float4*)&x[((size_t)(b * L_ + j0 + r)) * D_ + d0 + c];
  t[r][c + 0] = (f16)v.x; t[r][c + 1] = (f16)v.y;
  t[r][c + 2] = (f16)v.z; t[r][c + 3] = (f16)v.w;
  __syncthreads();
  union { f16 h[4]; uint2 u; } o;
  o.h[0] = t[c + 0][r]; o.h[1] = t[c + 1][r];
  o.h[2] = t[c + 2][r]; o.h[3] = t[c + 3][r];
  *(uint2*)&xT[((size_t)(b * D_ + d0 + r)) * L_ + j0 + c] = o.u;
}

// ---------------- K1: proj = relu(x @ W^T + b), f16 GEMM 64x64 tile ----------------
__global__ __launch_bounds__(256, 2) void proj_kernel(const float* __restrict__ x,
                                                      const float* __restrict__ W,
                                                      const float* __restrict__ bias,
                                                      f16* __restrict__ proj) {
  const int m0 = blockIdx.x << 6, n0 = blockIdx.y << 6;
  __shared__ f16 As[64 * 40], Bs[64 * 40];
  const int tid = threadIdx.x;
  const int wave = tid >> 6, lane = tid & 63;
  const int wr = wave >> 1, wc = wave & 1;
  const int quad = lane >> 4, l16 = lane & 15;
  const int srow = tid >> 2, scol = (tid & 3) << 3;

  f32x4 acc[2][2];
#pragma unroll
  for (int mt = 0; mt < 2; ++mt)
#pragma unroll
    for (int nt = 0; nt < 2; ++nt) acc[mt][nt] = (f32x4){0.f, 0.f, 0.f, 0.f};

  const float* xrow = &x[(size_t)(m0 + srow) * D_];
  const float* wrow = &W[(size_t)(n0 + srow) * D_];

  for (int kc = 0; kc < D_; kc += 32) {
    {
      float4 va = *(const float4*)&xrow[kc + scol];
      float4 vb = *(const float4*)&xrow[kc + scol + 4];
      union { f16 h[8]; uint4 u; } H;
      H.h[0] = (f16)va.x; H.h[1] = (f16)va.y; H.h[2] = (f16)va.z; H.h[3] = (f16)va.w;
      H.h[4] = (f16)vb.x; H.h[5] = (f16)vb.y; H.h[6] = (f16)vb.z; H.h[7] = (f16)vb.w;
      *(uint4*)&As[srow * 40 + scol] = H.u;
      float4 wa = *(const float4*)&wrow[kc + scol];
      float4 wb = *(const float4*)&wrow[kc + scol + 4];
      H.h[0] = (f16)wa.x; H.h[1] = (f16)wa.y; H.h[2] = (f16)wa.z; H.h[3] = (f16)wa.w;
      H.h[4] = (f16)wb.x; H.h[5] = (f16)wb.y; H.h[6] = (f16)wb.z; H.h[7] = (f16)wb.w;
      *(uint4*)&Bs[srow * 40 + scol] = H.u;
    }
    __syncthreads();
    f16x8 a0 = *(const f16x8*)&As[(wr * 32 + l16) * 40 + quad * 8];
    f16x8 a1 = *(const f16x8*)&As[(wr * 32 + 16 + l16) * 40 + quad * 8];
    f16x8 b0 = *(const f16x8*)&Bs[(wc * 32 + l16) * 40 + quad * 8];
    f16x8 b1 = *(const f16x8*)&Bs[(wc * 32 + 16 + l16) * 40 + quad * 8];
    acc[0][0] = MFMAH(a0, b0, acc[0][0]);
    acc[0][1] = MFMAH(a0, b1, acc[0][1]);
    acc[1][0] = MFMAH(a1, b0, acc[1][0]);
    acc[1][1] = MFMAH(a1, b1, acc[1][1]);
    __syncthreads();
  }
#pragma unroll
  for (int mt = 0; mt < 2; ++mt) {
#pragma unroll
    for (int nt = 0; nt < 2; ++nt) {
      const int n = n0 + wc * 32 + nt * 16 + l16;
      const float bv = bias[n];
#pragma unroll
      for (int r = 0; r < 4; ++r) {
        const int m = m0 + wr * 32 + mt * 16 + quad * 4 + r;
        proj[(size_t)m * D_ + n] = (f16)fmaxf(acc[mt][nt][r] + bv, 0.f);
      }
    }
  }
}

// ---------------- K2: fused flash attention, f16, XCD-pinned + pipelined ----------------
// LDS = 66048 (Qs) + 9728 (Ss) + 4608 (Ps) + 384 = 78.9 KB -> 2 blocks/CU.
__global__ __launch_bounds__(256, 2) void attn_kernel(const f16* __restrict__ proj,
                                                      const f16* __restrict__ xT,
                                                      const int* __restrict__ xmask,
                                                      float* __restrict__ out) {
  // XCD-pinned swizzle: round-robin block->XCD dispatch means blockIdx.x % 8 = XCD.
  // Pin batch b to XCD b so all 64 blocks of a batch share one L2.
  const int b = blockIdx.x & 7;
  const int i0 = (blockIdx.x >> 3) << 5;
  const int tid = threadIdx.x;
  const int wave = tid >> 6, lane = tid & 63;
  const int quad = lane >> 4, l16 = lane & 15;
  const int nbase = wave << 8;

  __shared__ f16 Qs[32 * 1032];
  __shared__ float Ss[32 * 76];
  __shared__ f16 Ps[32 * 72];
  __shared__ float m_s[32], l_s[32], fac_s[32];

  const f16* Qg = proj + ((size_t)(b * L_ + i0)) * D_;
#pragma unroll 4
  for (int idx = tid; idx < 32 * 128; idx += 256) {
    const int r = idx >> 7, c = (idx & 127) << 3;
    *(float4*)&Qs[r * 1032 + c] = *(const float4*)&Qg[(size_t)r * D_ + c];
  }
  if (tid < 32) { m_s[tid] = NEGF; l_s[tid] = 0.f; }

  f32x4 acc[2][16];
#pragma unroll
  for (int mt = 0; mt < 2; ++mt)
#pragma unroll
    for (int nt = 0; nt < 16; ++nt) acc[mt][nt] = (f32x4){0.f, 0.f, 0.f, 0.f};

  __syncthreads();

  const f16* Xg = xT + (size_t)b * D_ * L_;

  for (int jt = 0; jt < 32; ++jt) {
    const int j0 = jt << 6;
    const int jglob = j0 + (wave << 4) + l16;
    const bool masked = (xmask[b * L_ + jglob] != 0);

    // ---- Phase A: S = Q K^T, 4 acc chains, K loads pipelined 1 iter ahead ----
    f32x4 s0a = {0.f,0.f,0.f,0.f}, s0b = {0.f,0.f,0.f,0.f};
    f32x4 s1a = {0.f,0.f,0.f,0.f}, s1b = {0.f,0.f,0.f,0.f};
    const f16* Krow = proj + (size_t)(b * L_ + jglob) * D_;
    f16x8 k0 = *(const f16x8*)&Krow[quad * 8];
    f16x8 k1 = *(const f16x8*)&Krow[32 + quad * 8];
#pragma unroll
    for (int kc = 0; kc < D_; kc += 64) {
      f16x8 nk0, nk1;
      if (kc + 64 < D_) {
        nk0 = *(const f16x8*)&Krow[kc + 64 + quad * 8];
        nk1 = *(const f16x8*)&Krow[kc + 96 + quad * 8];
      }
      f16x8 qa0 = *(const f16x8*)&Qs[l16 * 1032 + kc + quad * 8];
      f16x8 qa1 = *(const f16x8*)&Qs[(16 + l16) * 1032 + kc + quad * 8];
      f16x8 qb0 = *(const f16x8*)&Qs[l16 * 1032 + kc + 32 + quad * 8];
      f16x8 qb1 = *(const f16x8*)&Qs[(16 + l16) * 1032 + kc + 32 + quad * 8];
      s0a = MFMAH(qa0, k0, s0a);
      s1a = MFMAH(qa1, k0, s1a);
      s0b = MFMAH(qb0, k1, s0b);
      s1b = MFMAH(qb1, k1, s1b);
      k0 = nk0; k1 = nk1;
    }

    // ---- Phase B: diag-zero, padding mask, stash S ----
#pragma unroll
    for (int mt = 0; mt < 2; ++mt) {
#pragma unroll
      for (int r = 0; r < 4; ++r) {
        const int irow = (mt << 4) + (quad << 2) + r;
        float v = mt ? (s1a[r] + s1b[r]) : (s0a[r] + s0b[r]);
        if (i0 + irow == jglob) v = 0.f;
        if (masked) v = NEGF;
        Ss[irow * 76 + (wave << 4) + l16] = v;
      }
    }
    __syncthreads();

    // ---- Phase C: online softmax (8 threads/row) ----
    {
      const int row = tid >> 3, part = tid & 7;
      const float* srow = &Ss[row * 76 + (part << 3)];
      const float4 sA = *(const float4*)srow;
      const float4 sB = *(const float4*)(srow + 4);
      float mx = fmaxf(fmaxf(fmaxf(sA.x, sA.y), fmaxf(sA.z, sA.w)),
                       fmaxf(fmaxf(sB.x, sB.y), fmaxf(sB.z, sB.w)));
      mx = fmaxf(mx, __shfl_xor(mx, 1));
      mx = fmaxf(mx, __shfl_xor(mx, 2));
      mx = fmaxf(mx, __shfl_xor(mx, 4));
      const float m_old = m_s[row];
      const float m_new = fmaxf(m_old, mx);
      float p[8];
      p[0] = __expf(sA.x - m_new); p[1] = __expf(sA.y - m_new);
      p[2] = __expf(sA.z - m_new); p[3] = __expf(sA.w - m_new);
      p[4] = __expf(sB.x - m_new); p[5] = __expf(sB.y - m_new);
      p[6] = __expf(sB.z - m_new); p[7] = __expf(sB.w - m_new);
      float sum = ((p[0] + p[1]) + (p[2] + p[3])) + ((p[4] + p[5]) + (p[6] + p[7]));
      sum += __shfl_xor(sum, 1);
      sum += __shfl_xor(sum, 2);
      sum += __shfl_xor(sum, 4);
      const float fac = __expf(m_old - m_new);
      if (part == 0) {
        m_s[row] = m_new;
        l_s[row] = l_s[row] * fac + sum;
        fac_s[row] = fac;
      }
      union { f16 h[8]; uint4 u; } hp;
#pragma unroll
      for (int i = 0; i < 8; ++i) hp.h[i] = (f16)p[i];
      *(uint4*)&Ps[row * 72 + (part << 3)] = hp.u;
    }
    __syncthreads();

    // ---- Phase D: rescale O, then O += P @ X; X loads pipelined 1 nt ahead ----
    float facr[2][4];
#pragma unroll
    for (int mt = 0; mt < 2; ++mt)
#pragma unroll
      for (int r = 0; r < 4; ++r) facr[mt][r] = fac_s[(mt << 4) + (quad << 2) + r];
#pragma unroll
    for (int mt = 0; mt < 2; ++mt)
#pragma unroll
      for (int nt = 0; nt < 16; ++nt)
#pragma unroll
        for (int r = 0; r < 4; ++r) acc[mt][nt][r] *= facr[mt][r];

    f16x8 pa[2][2];
#pragma unroll
    for (int mt = 0; mt < 2; ++mt)
#pragma unroll
      for (int kt = 0; kt < 2; ++kt)
        pa[mt][kt] = *(const f16x8*)&Ps[((mt << 4) + l16) * 72 + (kt << 5) + quad * 8];

    const f16* Xrow0 = Xg + (size_t)(nbase + l16) * L_ + j0;
    f16x8 xb0 = *(const f16x8*)&Xrow0[quad * 8];
    f16x8 xb1 = *(const f16x8*)&Xrow0[32 + quad * 8];
#pragma unroll
    for (int nt = 0; nt < 16; ++nt) {
      f16x8 nx0, nx1;
      if (nt + 1 < 16) {
        const f16* Xn = Xg + (size_t)(nbase + ((nt + 1) << 4) + l16) * L_ + j0;
        nx0 = *(const f16x8*)&Xn[quad * 8];
        nx1 = *(const f16x8*)&Xn[32 + quad * 8];
      }
      acc[0][nt] = MFMAH(pa[0][0], xb0, acc[0][nt]);
      acc[0][nt] = MFMAH(pa[0][1], xb1, acc[0][nt]);
      acc[1][nt] = MFMAH(pa[1][0], xb0, acc[1][nt]);
      acc[1][nt] = MFMAH(pa[1][1], xb1, acc[1][nt]);
      xb0 = nx0; xb1 = nx1;
    }
  }

  // ---- epilogue: out = O / l ----
  float inv[2][4];
#pragma unroll
  for (int mt = 0; mt < 2; ++mt)
#pragma unroll
    for (int r = 0; r < 4; ++r) inv[mt][r] = 1.0f / l_s[(mt << 4) + (quad << 2) + r];
#pragma unroll
  for (int mt = 0; mt < 2; ++mt) {
#pragma unroll
    for (int nt = 0; nt < 16; ++nt) {
#pragma unroll
      for (int r = 0; r < 4; ++r) {
        const int row = i0 + (mt << 4) + (quad << 2) + r;
        const int col = nbase + (nt << 4) + l16;
        out[((size_t)(b * L_ + row)) * D_ + col] = acc[mt][nt][r] * inv[mt][r];
      }
    }
  }
}

extern "C" void kernel_launch(void* const* d_in, const int* in_sizes, int n_in,
                              void* d_out, int out_size, void* d_ws, size_t ws_size,
                              hipStream_t stream) {
  const float* x = (const float*)d_in[0];
  const int* xmask = (const int*)d_in[1];
  const float* W = (const float*)d_in[2];
  const float* bias = (const float*)d_in[3];
  float* out = (float*)d_out;

  const size_t elems = (size_t)B_ * L_ * D_;
  if (ws_size < 2 * elems * sizeof(f16)) return;
  f16* proj = (f16*)d_ws;
  f16* xT = proj + elems;

  transpose_kernel<<<dim3(L_ / 32, D_ / 32, B_), 256, 0, stream>>>(x, xT);
  proj_kernel<<<dim3((B_ * L_) / 64, D_ / 64), 256, 0, stream>>>(x, W, bias, proj);
  attn_kernel<<<dim3((L_ / 32) * B_), 256, 0, stream>>>(proj, xT, xmask, out);
}